// Round 1
// baseline (33.331 us; speedup 1.0000x reference)
//
#include <hip/hip_runtime.h>

// BackprojectDepth: out[b, 0:3, k] = depth[b, idx] * (inv_K[b,:3,:3] @ [gx, gy, 1])
//                   out[b, 3, k]   = 1.0
// where idx = top_k_indices[b,k], gx = idx % W, gy = idx / W.
// pix_coords input is a meshgrid -> recomputed arithmetically, never read.

#define BB 16
#define HH 384
#define WW 1280
#define HWSZ (HH * WW)
#define KK 131072
#define KQ (KK / 4)   // quads per batch = 32768

__global__ __launch_bounds__(256) void backproject_kernel(
    const float* __restrict__ depth,   // B*HW
    const float* __restrict__ invK,    // B*16
    const int*   __restrict__ topk,    // B*K
    float*       __restrict__ out)     // B*4*K
{
    const int tid = blockIdx.x * blockDim.x + threadIdx.x;  // over B*K/4
    const int b  = tid / KQ;          // block-uniform (KQ multiple of 256*? yes: 32768/256=128 blocks/batch)
    const int kq = tid - b * KQ;
    const int k0 = kq * 4;

    // 3x3 of inv_K for this batch (uniform address across block -> L1 broadcast)
    const float* __restrict__ M = invK + b * 16;
    const float m00 = M[0], m01 = M[1], m02 = M[2];
    const float m10 = M[4], m11 = M[5], m12 = M[6];
    const float m20 = M[8], m21 = M[9], m22 = M[10];

    const int4 idx4 = *reinterpret_cast<const int4*>(topk + b * KK + k0);
    const float* __restrict__ db = depth + b * HWSZ;

    const int idxs[4] = {idx4.x, idx4.y, idx4.z, idx4.w};
    float ox[4], oy[4], oz[4];
#pragma unroll
    for (int j = 0; j < 4; ++j) {
        const int idx = idxs[j];
        const float d  = db[idx];
        const float gx = (float)(idx % WW);
        const float gy = (float)(idx / WW);
        const float c0 = fmaf(m00, gx, fmaf(m01, gy, m02));
        const float c1 = fmaf(m10, gx, fmaf(m11, gy, m12));
        const float c2 = fmaf(m20, gx, fmaf(m21, gy, m22));
        ox[j] = d * c0;
        oy[j] = d * c1;
        oz[j] = d * c2;
    }

    float* __restrict__ ob = out + (size_t)b * 4 * KK + k0;
    *reinterpret_cast<float4*>(ob + 0 * KK) = make_float4(ox[0], ox[1], ox[2], ox[3]);
    *reinterpret_cast<float4*>(ob + 1 * KK) = make_float4(oy[0], oy[1], oy[2], oy[3]);
    *reinterpret_cast<float4*>(ob + 2 * KK) = make_float4(oz[0], oz[1], oz[2], oz[3]);
    *reinterpret_cast<float4*>(ob + 3 * KK) = make_float4(1.f, 1.f, 1.f, 1.f);
}

extern "C" void kernel_launch(void* const* d_in, const int* in_sizes, int n_in,
                              void* d_out, int out_size, void* d_ws, size_t ws_size,
                              hipStream_t stream) {
    const float* depth = (const float*)d_in[0];     // (B,1,H,W) f32
    const float* invK  = (const float*)d_in[1];     // (B,4,4) f32
    // d_in[2] = pix_coords — intentionally unused (recomputed from index)
    const int*   topk  = (const int*)d_in[3];       // (B,K) i32
    float* out = (float*)d_out;                     // (B,4,K) f32

    const int total_threads = BB * KK / 4;          // 524288
    const int block = 256;
    const int grid = total_threads / block;         // 2048
    backproject_kernel<<<grid, block, 0, stream>>>(depth, invK, topk, out);
}

// Round 3
// 18.300 us; speedup vs baseline: 1.8214x; 1.8214x over previous
//
#include <hip/hip_runtime.h>

// BackprojectDepth: out[b, 0:3, k] = depth[b, idx] * (inv_K[b,:3,:3] @ [gx, gy, 1])
//                   out[b, 3, k]   = 1.0
// idx = top_k_indices[b,k], gx = idx % W, gy = idx / W.
// pix_coords input is a meshgrid -> recomputed arithmetically, never read.
//
// Round 2/3 changes:
//  - XCD-aware block remap: grid=2048, blocks dispatch round-robin over 8 XCDs
//    (phys block i -> XCD i%8). Remap so XCD x processes batches 2x,2x+1 only:
//    per-XCD depth working set = 2*1.875MB = 3.75MB < 4MB L2 -> gathers hit L2.
//  - Nontemporal stores for the streaming 33.5MB output (don't evict depth from L2).
//  - Nontemporal load for the read-once index stream.
//  - Use native ext_vector_type(4) vectors (nontemporal builtins reject HIP_vector_type).

#define BB 16
#define HH 384
#define WW 1280
#define HWSZ (HH * WW)
#define KK 131072
#define NXCD 8
#define BLOCKS_PER_BATCH (KK / (256 * 4))    // 128
#define TOTAL_BLOCKS (BB * BLOCKS_PER_BATCH) // 2048

typedef float v4f __attribute__((ext_vector_type(4)));
typedef int   v4i __attribute__((ext_vector_type(4)));

__global__ __launch_bounds__(256) void backproject_kernel(
    const float* __restrict__ depth,   // B*HW
    const float* __restrict__ invK,    // B*16
    const int*   __restrict__ topk,    // B*K
    float*       __restrict__ out)     // B*4*K
{
    // Physical block i lands on XCD i%NXCD. Give XCD x a contiguous logical range.
    const int xcd  = blockIdx.x & (NXCD - 1);
    const int slot = blockIdx.x >> 3;                       // 0..255
    const int logical = xcd * (TOTAL_BLOCKS / NXCD) + slot; // 0..2047
    const int b   = logical >> 7;                           // /128 -> batch (2 batches per XCD)
    const int blk = logical & 127;                          // block within batch
    const int k0  = blk * 1024 + threadIdx.x * 4;

    // 3x3 of inv_K for this batch (uniform address across block -> broadcast)
    const float* __restrict__ M = invK + b * 16;
    const float m00 = M[0], m01 = M[1], m02 = M[2];
    const float m10 = M[4], m11 = M[5], m12 = M[6];
    const float m20 = M[8], m21 = M[9], m22 = M[10];

    const v4i idx4 = __builtin_nontemporal_load(
        reinterpret_cast<const v4i*>(topk + b * KK + k0));
    const float* __restrict__ db = depth + b * HWSZ;

    float ox[4], oy[4], oz[4];
#pragma unroll
    for (int j = 0; j < 4; ++j) {
        const int idx = idx4[j];
        const float d  = db[idx];
        const float gx = (float)(idx % WW);
        const float gy = (float)(idx / WW);
        const float c0 = fmaf(m00, gx, fmaf(m01, gy, m02));
        const float c1 = fmaf(m10, gx, fmaf(m11, gy, m12));
        const float c2 = fmaf(m20, gx, fmaf(m21, gy, m22));
        ox[j] = d * c0;
        oy[j] = d * c1;
        oz[j] = d * c2;
    }

    float* __restrict__ ob = out + (size_t)b * 4 * KK + k0;
    v4f vx = {ox[0], ox[1], ox[2], ox[3]};
    v4f vy = {oy[0], oy[1], oy[2], oy[3]};
    v4f vz = {oz[0], oz[1], oz[2], oz[3]};
    v4f vw = {1.f, 1.f, 1.f, 1.f};
    __builtin_nontemporal_store(vx, reinterpret_cast<v4f*>(ob + 0 * KK));
    __builtin_nontemporal_store(vy, reinterpret_cast<v4f*>(ob + 1 * KK));
    __builtin_nontemporal_store(vz, reinterpret_cast<v4f*>(ob + 2 * KK));
    __builtin_nontemporal_store(vw, reinterpret_cast<v4f*>(ob + 3 * KK));
}

extern "C" void kernel_launch(void* const* d_in, const int* in_sizes, int n_in,
                              void* d_out, int out_size, void* d_ws, size_t ws_size,
                              hipStream_t stream) {
    const float* depth = (const float*)d_in[0];     // (B,1,H,W) f32
    const float* invK  = (const float*)d_in[1];     // (B,4,4) f32
    // d_in[2] = pix_coords — intentionally unused (recomputed from index)
    const int*   topk  = (const int*)d_in[3];       // (B,K) i32
    float* out = (float*)d_out;                     // (B,4,K) f32

    backproject_kernel<<<TOTAL_BLOCKS, 256, 0, stream>>>(depth, invK, topk, out);
}